// Round 7
// baseline (345.419 us; speedup 1.0000x reference)
//
#include <hip/hip_runtime.h>
#include <hip/hip_bf16.h>
#include <cmath>

typedef unsigned short u16;
typedef unsigned int   u32;

#define BB 4
#define CC 1024
#define TT 4096
#define HH 16
#define DD 64

using bf16x8 = __attribute__((ext_vector_type(8))) __bf16;
using f32x4  = __attribute__((ext_vector_type(4))) float;

union FragU { bf16x8 v; u16 u[8]; };

__device__ __forceinline__ float bf2f(u16 u) {
    union { u32 i; float f; } v; v.i = ((u32)u) << 16; return v.f;
}
__device__ __forceinline__ u16 f2bf(float f) {
    union { float f; u32 i; } v; v.f = f;
    u32 x = v.i;
    return (u16)((x + 0x7fffu + ((x >> 16) & 1u)) >> 16);  // RNE
}

// async global->LDS, 16B per lane: LDS dest = wave-uniform base + lane*16
__device__ __forceinline__ void gl_lds16(const u16* g, u16* l) {
    __builtin_amdgcn_global_load_lds(
        (const __attribute__((address_space(1))) void*)g,
        (__attribute__((address_space(3))) void*)l, 16, 0, 0);
}

// ---------------------------------------------------------------------------
// Fused prep: zone 0 (ids 0..1023)    x fp32 [B][C][T] -> xt bf16 [B][T][C]
//             (float4-vectorized loads: 16 loads/thread, was 64 scalar)
//             zone 1 (ids 1024..5119) weight fp32->bf16 cvt (Wq,Wk,Wv,Wo)
//             zone 2 (ids 5120..5379) zero kvbuf+ksum (266240 floats)
// ---------------------------------------------------------------------------
__global__ __launch_bounds__(256) void prep_kernel(
    const float* __restrict__ x,
    const float* __restrict__ Wq, const float* __restrict__ Wk,
    const float* __restrict__ Wv, const float* __restrict__ Wo,
    u16* __restrict__ xt, u16* __restrict__ Wcat, u16* __restrict__ Wob,
    float* __restrict__ kvz)
{
    __shared__ u16 tile[64 * 258];
    const int id  = blockIdx.x;
    const int tid = threadIdx.x;

    if (id < 1024) {
        const int t0 = (id & 63) * 64;
        const int c0 = ((id >> 6) & 3) * 256;
        const int b  = id >> 8;
        const float* xb  = x  + (size_t)b * CC * TT;
        u16*         xtb = xt + (size_t)b * TT * CC;
        const int t4 = (tid & 15) * 4;       // 0..60, 4 t per thread
        const int cl = tid >> 4;             // 0..15
        #pragma unroll
        for (int q = 0; q < 16; ++q) {
            const int cr = q * 16 + cl;      // 0..255
            const float4 v = *reinterpret_cast<const float4*>(
                &xb[(size_t)(c0 + cr) * TT + t0 + t4]);
            tile[(t4 + 0) * 258 + cr] = f2bf(v.x);
            tile[(t4 + 1) * 258 + cr] = f2bf(v.y);
            tile[(t4 + 2) * 258 + cr] = f2bf(v.z);
            tile[(t4 + 3) * 258 + cr] = f2bf(v.w);
        }
        __syncthreads();
        const int cp = tid & 127;
        const int th = tid >> 7;
        #pragma unroll 8
        for (int q = 0; q < 32; ++q) {
            const int tr = q * 2 + th;
            const u32 v = *reinterpret_cast<const u32*>(&tile[tr * 258 + cp * 2]);
            *reinterpret_cast<u32*>(&xtb[(size_t)(t0 + tr) * CC + c0 + cp * 2]) = v;
        }
    } else if (id < 5120) {
        const int id2  = id - 1024;
        const int wsel = id2 >> 10;
        const int i    = ((id2 & 1023) * 256 + tid) * 4;
        const float* src = (wsel == 0) ? Wq : (wsel == 1) ? Wk : (wsel == 2) ? Wv : Wo;
        u16* dst = (wsel < 3) ? (Wcat + (size_t)wsel * CC * CC) : Wob;
        const float4 v = *reinterpret_cast<const float4*>(src + i);
        ushort4 o;
        o.x = f2bf(v.x); o.y = f2bf(v.y); o.z = f2bf(v.z); o.w = f2bf(v.w);
        *reinterpret_cast<ushort4*>(dst + i) = o;
    } else {
        const int idx = ((id - 5120) * 256 + tid) * 4;   // 260*1024 = 266240 exact
        *reinterpret_cast<float4*>(&kvz[idx]) = (float4){0.f, 0.f, 0.f, 0.f};
    }
}

// ---------------------------------------------------------------------------
// kvfuse MT=2: per block (head-pair n, TWO adjacent 128-row m-tiles):
//   for mt in 0,1:
//     1) GEMM: K_tile = xt @ Wk_n^T, V_tile = xt @ Wv_n^T (A shared staging)
//     2) bias/elu -> transposed swizzled LDS (two-pass t-halves) ->
//        contract into PERSISTENT register accumulators ckv/cks
//   atomics ONCE per block (halved vs MT=1).
// LDS: staging 48K (As/WKs/WVs) + Kl/Vl 32K (dedicated) = 80K -> 2 blocks/CU.
// mt-boundary: next tile's first k-step staging pre-issued BEFORE the
// contraction; contraction barriers are lgkm-only (no vmcnt drain) so the
// loads stay in flight underneath.
// Grid 512, XCD swizzle: XCD r owns m rows [r*2048,(r+1)*2048) x all 8 n.
// ---------------------------------------------------------------------------
__global__ __launch_bounds__(256, 2) void kvfuse_kernel(
    const u16* __restrict__ A, const u16* __restrict__ Wk,
    const u16* __restrict__ Wv, const float* __restrict__ bk,
    const float* __restrict__ bv, float* __restrict__ kv,
    float* __restrict__ ksum)
{
    __shared__ __align__(16) char smem[81920];
    u16* As  = (u16*)smem;              // [128][64] staging
    u16* WKs = (u16*)(smem + 16384);
    u16* WVs = (u16*)(smem + 32768);
    u16* Kl  = (u16*)(smem + 49152);    // [c:128][t:64] swizzled
    u16* Vl  = (u16*)(smem + 65536);

    const int tid  = threadIdx.x;
    const int w    = tid >> 6;
    const int lane = tid & 63;
    const int wm = w >> 1, wn = w & 1;
    const int quad = lane >> 4, l16 = lane & 15;

    // XCD swizzle: 512 blocks; XCD r -> sw in [r*64,(r+1)*64)
    const int bid = blockIdx.x;
    const int sw  = (bid & 7) * 64 + (bid >> 3);
    const int n0  = (sw & 7) * 128;      // head-pair channel base
    const int mb  = (sw >> 3) * 256;     // m-pair base row (same b for both mt)

    const int srow = lane >> 3;
    const int scol = ((lane & 7) ^ srow) * 8;

    const int hh    = w >> 1;            // head within pair (contraction)
    const int dbase = (w & 1) * 32;
    const int b     = mb >> 12;
    const int bh    = b * HH + (sw & 7) * 2 + hh;

    float bkk[4], bvv[4];
    #pragma unroll
    for (int j = 0; j < 4; ++j) {
        bkk[j] = bk[n0 + wn * 64 + j * 16 + l16];
        bvv[j] = bv[n0 + wn * 64 + j * 16 + l16];
    }

    FragU ones;
    #pragma unroll
    for (int j = 0; j < 8; ++j) ones.u[j] = (l16 == 0) ? 0x3F80u : 0u;

    f32x4 ckv[2][4], cks[2];
    #pragma unroll
    for (int s = 0; s < 2; ++s) {
        cks[s] = (f32x4)0.0f;
        #pragma unroll
        for (int e4 = 0; e4 < 4; ++e4) ckv[s][e4] = (f32x4)0.0f;
    }

#define STAGE(M0, K0)                                                               \
    { _Pragma("unroll")                                                             \
      for (int s_ = 0; s_ < 4; ++s_) {                                              \
        gl_lds16(A  + (size_t)((M0) + 32 * w + 8 * s_ + srow) * CC + (K0) * 64 + scol, \
                 &As [(32 * w + 8 * s_) * 64]);                                     \
        gl_lds16(Wk + (size_t)(n0 + 32 * w + 8 * s_ + srow) * CC + (K0) * 64 + scol,   \
                 &WKs[(32 * w + 8 * s_) * 64]);                                     \
        gl_lds16(Wv + (size_t)(n0 + 32 * w + 8 * s_ + srow) * CC + (K0) * 64 + scol,   \
                 &WVs[(32 * w + 8 * s_) * 64]); } }

#define BARL() { asm volatile("s_waitcnt lgkmcnt(0)" ::: "memory"); \
                 __builtin_amdgcn_s_barrier();                      \
                 asm volatile("" ::: "memory"); }

    // pre-issue first tile's first k-step
    STAGE(mb, 0);

    for (int mt = 0; mt < 2; ++mt) {
        const int m0 = mb + mt * 128;

        f32x4 ak[4][4], av[4][4];
        #pragma unroll
        for (int i = 0; i < 4; ++i)
            #pragma unroll
            for (int j = 0; j < 4; ++j) { ak[i][j] = (f32x4)0.0f; av[i][j] = (f32x4)0.0f; }

        for (int ks = 0; ks < 16; ++ks) {
            if (ks > 0) {
                __syncthreads();          // prev compute done reading staging
                STAGE(m0, ks);
            }
            __syncthreads();              // drain loads + sync

            #pragma unroll
            for (int sub = 0; sub < 2; ++sub) {
                const int pg = (((sub << 2) | quad) ^ (l16 & 7)) * 8;
                bf16x8 af[4], bk4[4], bv4[4];
                #pragma unroll
                for (int i = 0; i < 4; ++i) {
                    af[i]  = *reinterpret_cast<const bf16x8*>(&As [(wm * 64 + i * 16 + l16) * 64 + pg]);
                    bk4[i] = *reinterpret_cast<const bf16x8*>(&WKs[(wn * 64 + i * 16 + l16) * 64 + pg]);
                    bv4[i] = *reinterpret_cast<const bf16x8*>(&WVs[(wn * 64 + i * 16 + l16) * 64 + pg]);
                }
                #pragma unroll
                for (int i = 0; i < 4; ++i)
                    #pragma unroll
                    for (int j = 0; j < 4; ++j) {
                        ak[i][j] = __builtin_amdgcn_mfma_f32_16x16x32_bf16(af[i], bk4[j], ak[i][j], 0, 0, 0);
                        av[i][j] = __builtin_amdgcn_mfma_f32_16x16x32_bf16(af[i], bv4[j], av[i][j], 0, 0, 0);
                    }
            }
        }

        __syncthreads();                  // all waves done reading staging
        if (mt == 0) STAGE(mb + 128, 0);  // pre-issue next tile (hidden below)

        // ---- two-pass activation+transpose -> contraction (lgkm-only bars) --
        #pragma unroll
        for (int h = 0; h < 2; ++h) {
            BARL();                       // prior contract reads complete
            if (wm == h) {
                #pragma unroll
                for (int i = 0; i < 4; ++i) {
                    const int t6 = i * 16 + quad * 4;          // 0..60
                    #pragma unroll
                    for (int j = 0; j < 4; ++j) {
                        const int c    = wn * 64 + j * 16 + l16;
                        const int toff = t6 ^ ((c & 7) * 8);
                        ushort4 oK, oV;
                        #pragma unroll
                        for (int r = 0; r < 4; ++r) {
                            float vK = ak[i][j][r] + bkk[j];
                            vK = (vK > 0.0f) ? (vK + 1.0f) : __expf(vK);
                            ((u16*)&oK)[r] = f2bf(vK);
                            ((u16*)&oV)[r] = f2bf(av[i][j][r] + bvv[j]);
                        }
                        *reinterpret_cast<ushort4*>(&Kl[c * 64 + toff]) = oK;
                        *reinterpret_cast<ushort4*>(&Vl[c * 64 + toff]) = oV;
                    }
                }
            }
            BARL();                       // writes visible
            #pragma unroll
            for (int kt = 0; kt < 2; ++kt) {
                const int tg = kt * 32 + quad * 8;
                #pragma unroll
                for (int s = 0; s < 2; ++s) {
                    const int ca = hh * 64 + dbase + s * 16 + l16;
                    const bf16x8 af = *reinterpret_cast<const bf16x8*>(
                        &Kl[ca * 64 + (tg ^ ((ca & 7) * 8))]);
                    #pragma unroll
                    for (int e4 = 0; e4 < 4; ++e4) {
                        const int cb = hh * 64 + e4 * 16 + l16;
                        const bf16x8 bfv = *reinterpret_cast<const bf16x8*>(
                            &Vl[cb * 64 + (tg ^ ((cb & 7) * 8))]);
                        ckv[s][e4] = __builtin_amdgcn_mfma_f32_16x16x32_bf16(af, bfv, ckv[s][e4], 0, 0, 0);
                    }
                    cks[s] = __builtin_amdgcn_mfma_f32_16x16x32_bf16(af, ones.v, cks[s], 0, 0, 0);
                }
            }
        }
    }
#undef BARL
#undef STAGE

    float* kvb = kv + (size_t)bh * DD * DD;
    #pragma unroll
    for (int s = 0; s < 2; ++s)
        #pragma unroll
        for (int e4 = 0; e4 < 4; ++e4)
            #pragma unroll
            for (int r = 0; r < 4; ++r)
                atomicAdd(&kvb[(dbase + s * 16 + quad * 4 + r) * DD + e4 * 16 + l16],
                          ckv[s][e4][r]);
    if (l16 == 0) {
        #pragma unroll
        for (int s = 0; s < 2; ++s)
            #pragma unroll
            for (int r = 0; r < 4; ++r)
                atomicAdd(&ksum[bh * DD + dbase + s * 16 + quad * 4 + r], cks[s][r]);
    }
}

// ---------------------------------------------------------------------------
// qattn: Q-GEMM (N=1024) with attn fused in the epilogue (unchanged):
//   Q tile (bias+elu+1) -> swizzled LDS Qt[t:128][c:128]
//   then per wave (head hh=w>>1, t-half th=w&1): num = Q.kv, z = Q.ksum,
//   out = num/(z+1e-6) -> bf16 attn tile (kv/ksum from L2-hot global).
// 1D grid 1024 with XCD swizzle.
// ---------------------------------------------------------------------------
__global__ __launch_bounds__(256, 2) void qattn_kernel(
    const u16* __restrict__ A, const u16* __restrict__ Wq,
    const float* __restrict__ bq, const float* __restrict__ kv,
    const float* __restrict__ ksum, u16* __restrict__ attnO)
{
    __shared__ __align__(16) char smem[32768];
    u16* As = (u16*)smem;                  // [128][64]
    u16* Ws = (u16*)(smem + 16384);

    const int tid  = threadIdx.x;
    const int w    = tid >> 6;
    const int lane = tid & 63;
    const int wm = w >> 1, wn = w & 1;
    const int quad = lane >> 4, l16 = lane & 15;
    const int l7 = l16 & 7;

    const int bid = blockIdx.x;
    const int sw  = (bid & 7) * 128 + (bid >> 3);
    const int n0  = (sw & 7) * 128;
    const int m0  = (sw >> 3) * 128;

    const int srow = lane >> 3;
    const int scol = ((lane & 7) ^ srow) * 8;

    f32x4 acc[4][4];
    #pragma unroll
    for (int i = 0; i < 4; ++i)
        #pragma unroll
        for (int j = 0; j < 4; ++j) acc[i][j] = (f32x4)0.0f;

    for (int k0 = 0; k0 < CC; k0 += 64) {
        __syncthreads();
        #pragma unroll
        for (int s = 0; s < 4; ++s) {
            gl_lds16(A  + (size_t)(m0 + 32 * w + 8 * s + srow) * CC + k0 + scol,
                     &As[(32 * w + 8 * s) * 64]);
            gl_lds16(Wq + (size_t)(n0 + 32 * w + 8 * s + srow) * CC + k0 + scol,
                     &Ws[(32 * w + 8 * s) * 64]);
        }
        __syncthreads();

        #pragma unroll
        for (int sub = 0; sub < 2; ++sub) {
            const int pg = (((sub << 2) | quad) ^ l7) * 8;
            bf16x8 af[4], bfr[4];
            #pragma unroll
            for (int i = 0; i < 4; ++i) {
                af[i]  = *reinterpret_cast<const bf16x8*>(&As[(wm * 64 + i * 16 + l16) * 64 + pg]);
                bfr[i] = *reinterpret_cast<const bf16x8*>(&Ws[(wn * 64 + i * 16 + l16) * 64 + pg]);
            }
            #pragma unroll
            for (int i = 0; i < 4; ++i)
                #pragma unroll
                for (int j = 0; j < 4; ++j)
                    acc[i][j] = __builtin_amdgcn_mfma_f32_16x16x32_bf16(af[i], bfr[j], acc[i][j], 0, 0, 0);
        }
    }

    // ---- Q activation -> swizzled LDS tile ----
    __syncthreads();
    u16* Qt = (u16*)smem;                  // [t:128][c:128] swizzled
    float bqq[4];
    #pragma unroll
    for (int j = 0; j < 4; ++j) bqq[j] = bq[n0 + wn * 64 + j * 16 + l16];
    #pragma unroll
    for (int i = 0; i < 4; ++i) {
        #pragma unroll
        for (int j = 0; j < 4; ++j) {
            const int c = wn * 64 + j * 16 + l16;
            #pragma unroll
            for (int r = 0; r < 4; ++r) {
                const int t = wm * 64 + i * 16 + quad * 4 + r;
                float v = acc[i][j][r] + bqq[j];
                v = (v > 0.0f) ? (v + 1.0f) : __expf(v);
                Qt[t * 128 + (c ^ ((t & 7) * 8))] = f2bf(v);
            }
        }
    }
    __syncthreads();

    // ---- attn epilogue: wave -> head hh, t-half th ----
    const int hh = w >> 1, th = w & 1;
    const int b  = m0 >> 12;
    const int bh = b * HH + (sw & 7) * 2 + hh;
    const float* kvh = kv + (size_t)bh * DD * DD;

    FragU bf[4][2], zb[2];
    #pragma unroll
    for (int ck = 0; ck < 2; ++ck) {
        #pragma unroll
        for (int nt = 0; nt < 4; ++nt)
            #pragma unroll
            for (int j = 0; j < 8; ++j)
                bf[nt][ck].u[j] = f2bf(kvh[(ck * 32 + quad * 8 + j) * DD + nt * 16 + l16]);
        #pragma unroll
        for (int j = 0; j < 8; ++j)
            zb[ck].u[j] = (l16 == 0) ? f2bf(ksum[bh * DD + ck * 32 + quad * 8 + j]) : 0u;
    }

    f32x4 a2[4][4], za[4];
    #pragma unroll
    for (int i = 0; i < 4; ++i) {
        za[i] = (f32x4)0.0f;
        #pragma unroll
        for (int j = 0; j < 4; ++j) a2[i][j] = (f32x4)0.0f;
    }

    #pragma unroll
    for (int i = 0; i < 4; ++i) {
        const int trow = th * 64 + i * 16 + l16;
        #pragma unroll
        for (int ck = 0; ck < 2; ++ck) {
            const bf16x8 af = *reinterpret_cast<const bf16x8*>(
                &Qt[trow * 128 + (((hh * 8 + ck * 4 + quad) ^ l7) * 8)]);
            #pragma unroll
            for (int nt = 0; nt < 4; ++nt)
                a2[i][nt] = __builtin_amdgcn_mfma_f32_16x16x32_bf16(af, bf[nt][ck].v, a2[i][nt], 0, 0, 0);
            za[i] = __builtin_amdgcn_mfma_f32_16x16x32_bf16(af, zb[ck].v, za[i], 0, 0, 0);
        }
    }

    #pragma unroll
    for (int i = 0; i < 4; ++i) {
        float inv[4];
        #pragma unroll
        for (int r = 0; r < 4; ++r) {
            const float zv = __shfl(za[i][r], lane & 48);
            inv[r] = 1.0f / (zv + 1e-6f);
        }
        #pragma unroll
        for (int nt = 0; nt < 4; ++nt) {
            #pragma unroll
            for (int r = 0; r < 4; ++r) {
                const size_t row = (size_t)(m0 + th * 64 + i * 16 + quad * 4 + r);
                const int    col = n0 + hh * 64 + nt * 16 + l16;
                attnO[row * CC + col] = f2bf(a2[i][nt][r] * inv[r]);
            }
        }
    }
}

// ---------------------------------------------------------------------------
// Out-proj GEMM (MODE 2): 128x128 tile, +bias +fp32 residual, LDS-bounced
// fp32 stores along T.  1D grid 1024 with XCD swizzle. (unchanged)
// ---------------------------------------------------------------------------
template <int MODE>
__global__ __launch_bounds__(256, 2) void gemm_kernel(
    const u16* __restrict__ A, const u16* __restrict__ W,
    const float* __restrict__ b0, const float* __restrict__ b1,
    const float* __restrict__ b2, u16* __restrict__ Ybf,
    float* __restrict__ Yf, const float* __restrict__ xres,
    int M, int N, int K)
{
    __shared__ char smem[34048];           // As+Ws (32KB) / Cs (64*133*4)
    u16* As = (u16*)smem;                  // [128][64]
    u16* Ws = (u16*)(smem + 16384);        // [128][64]

    const int tid  = threadIdx.x;
    const int w    = tid >> 6;
    const int lane = tid & 63;
    const int wm = w >> 1, wn = w & 1;
    const int quad = lane >> 4, l16 = lane & 15;

    const int bid = blockIdx.x;
    const int sw  = (bid & 7) * 128 + (bid >> 3);
    const int n0  = (sw & 7) * 128;
    const int m0  = (sw >> 3) * 128;

    const int srow = lane >> 3;
    const int scol = ((lane & 7) ^ srow) * 8;

    f32x4 acc[4][4];
    #pragma unroll
    for (int i = 0; i < 4; ++i)
        #pragma unroll
        for (int j = 0; j < 4; ++j) acc[i][j] = (f32x4)0.0f;

    for (int k0 = 0; k0 < K; k0 += 64) {
        __syncthreads();
        #pragma unroll
        for (int s = 0; s < 4; ++s)
            gl_lds16(A + (size_t)(m0 + 32 * w + 8 * s + srow) * K + k0 + scol,
                     &As[(32 * w + 8 * s) * 64]);
        #pragma unroll
        for (int s = 0; s < 4; ++s)
            gl_lds16(W + (size_t)(n0 + 32 * w + 8 * s + srow) * K + k0 + scol,
                     &Ws[(32 * w + 8 * s) * 64]);
        __syncthreads();

        #pragma unroll
        for (int sub = 0; sub < 2; ++sub) {
            const int pg = (((sub << 2) | quad) ^ (l16 & 7)) * 8;
            bf16x8 af[4], bfr[4];
            #pragma unroll
            for (int i = 0; i < 4; ++i) {
                af[i]  = *reinterpret_cast<const bf16x8*>(&As[(wm * 64 + i * 16 + l16) * 64 + pg]);
                bfr[i] = *reinterpret_cast<const bf16x8*>(&Ws[(wn * 64 + i * 16 + l16) * 64 + pg]);
            }
            #pragma unroll
            for (int i = 0; i < 4; ++i)
                #pragma unroll
                for (int j = 0; j < 4; ++j)
                    acc[i][j] = __builtin_amdgcn_mfma_f32_16x16x32_bf16(af[i], bfr[j], acc[i][j], 0, 0, 0);
        }
    }

    if (MODE == 2) {
        float* Cs = (float*)smem;          // [64][133]
        const int b     = m0 / TT;
        const int tbase = m0 - b * TT;
        const int cl    = lane >> 4;
        #pragma unroll
        for (int hh = 0; hh < 2; ++hh) {
            __syncthreads();
            if (wm == hh) {
                #pragma unroll
                for (int i = 0; i < 4; ++i)
                    #pragma unroll
                    for (int j = 0; j < 4; ++j)
                        #pragma unroll
                        for (int r = 0; r < 4; ++r)
                            Cs[(i * 16 + quad * 4 + r) * 133 + wn * 64 + j * 16 + l16] = acc[i][j][r];
            }
            __syncthreads();
            #pragma unroll
            for (int p = 0; p < 8; ++p) {
                const int col = p * 16 + w * 4 + cl;
                const int tl  = l16 * 4;
                float4 v;
                v.x = Cs[(tl + 0) * 133 + col];
                v.y = Cs[(tl + 1) * 133 + col];
                v.z = Cs[(tl + 2) * 133 + col];
                v.w = Cs[(tl + 3) * 133 + col];
                const float bv = b0[n0 + col];
                const size_t base = ((size_t)b * CC + n0 + col) * TT + tbase + hh * 64 + tl;
                const float4 rx = *reinterpret_cast<const float4*>(&xres[base]);
                v.x += bv + rx.x; v.y += bv + rx.y;
                v.z += bv + rx.z; v.w += bv + rx.w;
                *reinterpret_cast<float4*>(&Yf[base]) = v;
            }
        }
    }
}

// ---------------------------------------------------------------------------
extern "C" void kernel_launch(void* const* d_in, const int* in_sizes, int n_in,
                              void* d_out, int out_size, void* d_ws, size_t ws_size,
                              hipStream_t stream)
{
    const float* x  = (const float*)d_in[0];
    const float* Wq = (const float*)d_in[1];
    const float* bq = (const float*)d_in[2];
    const float* Wk = (const float*)d_in[3];
    const float* bk = (const float*)d_in[4];
    const float* Wv = (const float*)d_in[5];
    const float* bv = (const float*)d_in[6];
    const float* Wo = (const float*)d_in[7];
    const float* bo = (const float*)d_in[8];
    float* out = (float*)d_out;

    const int M = BB * TT;                                   // 16384
    const size_t BUF  = (size_t)BB * TT * CC * sizeof(u16);  // 32 MiB
    const size_t WBUF = (size_t)CC * CC * sizeof(u16);       // 2 MiB

    char* ws = (char*)d_ws;
    u16* xt   = (u16*)(ws);                // xt bf16 [B*T][C]
    u16* Qb   = (u16*)(ws + BUF);          // attn output [B*T][C]
    u16* Wcat = (u16*)(ws + 4 * BUF);      // [3072][1024] bf16 (Q,K,V)
    u16* Wob  = (u16*)(ws + 4 * BUF + 3 * WBUF);
    float* kvbuf = (float*)(ws + 4 * BUF + 4 * WBUF);        // 1 MiB + 16 KiB (incl ksum)
    float* ksumb = kvbuf + (size_t)BB * HH * DD * DD;

    // prep: transpose (1024, float4-vectorized) + weight cvt (4096) + zero (260)
    prep_kernel<<<5380, 256, 0, stream>>>(x, Wq, Wk, Wv, Wo, xt, Wcat, Wob, kvbuf);

    // fused K/V GEMM + kv/ksum contraction, MT=2 (atomic accumulate)
    kvfuse_kernel<<<512, 256, 0, stream>>>(
        xt, Wcat + (size_t)CC * CC, Wcat + 2 * (size_t)CC * CC, bk, bv, kvbuf, ksumb);

    // fused Q GEMM + attention epilogue -> attn tile in Qb
    qattn_kernel<<<1024, 256, 0, stream>>>(
        xt, Wcat, bq, kvbuf, ksumb, Qb);

    // out-proj + bias + residual -> fp32 [B][C][T]
    gemm_kernel<2><<<1024, 256, 0, stream>>>(
        Qb, Wob, bo, nullptr, nullptr, nullptr, out, x, M, CC, CC);
}

// Round 8
// 321.787 us; speedup vs baseline: 1.0734x; 1.0734x over previous
//
#include <hip/hip_runtime.h>
#include <hip/hip_bf16.h>
#include <cmath>

typedef unsigned short u16;
typedef unsigned int   u32;

#define BB 4
#define CC 1024
#define TT 4096
#define HH 16
#define DD 64

using bf16x8 = __attribute__((ext_vector_type(8))) __bf16;
using f32x4  = __attribute__((ext_vector_type(4))) float;

union FragU { bf16x8 v; u16 u[8]; };

__device__ __forceinline__ float bf2f(u16 u) {
    union { u32 i; float f; } v; v.i = ((u32)u) << 16; return v.f;
}
__device__ __forceinline__ u16 f2bf(float f) {
    union { float f; u32 i; } v; v.f = f;
    u32 x = v.i;
    return (u16)((x + 0x7fffu + ((x >> 16) & 1u)) >> 16);  // RNE
}

// async global->LDS, 16B per lane: LDS dest = wave-uniform base + lane*16
__device__ __forceinline__ void gl_lds16(const u16* g, u16* l) {
    __builtin_amdgcn_global_load_lds(
        (const __attribute__((address_space(1))) void*)g,
        (__attribute__((address_space(3))) void*)l, 16, 0, 0);
}

// ---------------------------------------------------------------------------
// Fused prep: zone 0 (ids 0..1023)    x fp32 [B][C][T] -> xt bf16 [B][T][C]
//             (float4-vectorized loads: confirmed ~16 us win, round 7)
//             zone 1 (ids 1024..5119) weight fp32->bf16 cvt (Wq,Wk,Wv,Wo)
//             zone 2 (ids 5120..5379) zero kvbuf+ksum (266240 floats)
// ---------------------------------------------------------------------------
__global__ __launch_bounds__(256) void prep_kernel(
    const float* __restrict__ x,
    const float* __restrict__ Wq, const float* __restrict__ Wk,
    const float* __restrict__ Wv, const float* __restrict__ Wo,
    u16* __restrict__ xt, u16* __restrict__ Wcat, u16* __restrict__ Wob,
    float* __restrict__ kvz)
{
    __shared__ u16 tile[64 * 258];
    const int id  = blockIdx.x;
    const int tid = threadIdx.x;

    if (id < 1024) {
        const int t0 = (id & 63) * 64;
        const int c0 = ((id >> 6) & 3) * 256;
        const int b  = id >> 8;
        const float* xb  = x  + (size_t)b * CC * TT;
        u16*         xtb = xt + (size_t)b * TT * CC;
        const int t4 = (tid & 15) * 4;       // 0..60, 4 t per thread
        const int cl = tid >> 4;             // 0..15
        #pragma unroll
        for (int q = 0; q < 16; ++q) {
            const int cr = q * 16 + cl;      // 0..255
            const float4 v = *reinterpret_cast<const float4*>(
                &xb[(size_t)(c0 + cr) * TT + t0 + t4]);
            tile[(t4 + 0) * 258 + cr] = f2bf(v.x);
            tile[(t4 + 1) * 258 + cr] = f2bf(v.y);
            tile[(t4 + 2) * 258 + cr] = f2bf(v.z);
            tile[(t4 + 3) * 258 + cr] = f2bf(v.w);
        }
        __syncthreads();
        const int cp = tid & 127;
        const int th = tid >> 7;
        #pragma unroll 8
        for (int q = 0; q < 32; ++q) {
            const int tr = q * 2 + th;
            const u32 v = *reinterpret_cast<const u32*>(&tile[tr * 258 + cp * 2]);
            *reinterpret_cast<u32*>(&xtb[(size_t)(t0 + tr) * CC + c0 + cp * 2]) = v;
        }
    } else if (id < 5120) {
        const int id2  = id - 1024;
        const int wsel = id2 >> 10;
        const int i    = ((id2 & 1023) * 256 + tid) * 4;
        const float* src = (wsel == 0) ? Wq : (wsel == 1) ? Wk : (wsel == 2) ? Wv : Wo;
        u16* dst = (wsel < 3) ? (Wcat + (size_t)wsel * CC * CC) : Wob;
        const float4 v = *reinterpret_cast<const float4*>(src + i);
        ushort4 o;
        o.x = f2bf(v.x); o.y = f2bf(v.y); o.z = f2bf(v.z); o.w = f2bf(v.w);
        *reinterpret_cast<ushort4*>(dst + i) = o;
    } else {
        const int idx = ((id - 5120) * 256 + tid) * 4;   // 260*1024 = 266240 exact
        *reinterpret_cast<float4*>(&kvz[idx]) = (float4){0.f, 0.f, 0.f, 0.f};
    }
}

// ---------------------------------------------------------------------------
// kvfuse (round-6 proven form, MT=1): per block (head-pair n, 128-row m-tile):
//   1) GEMM: K_tile = xt @ Wk_n^T, V_tile = xt @ Wv_n^T (A shared)
//   2+3) TWO-PASS (t-halves, 48KB peak LDS):
//        pass h: waves wm==h write their 64-t half (bias/elu, transposed
//        swizzled [c:128][t:64], idx = c*64 + (t ^ ((c&7)*8))); then ALL
//        waves contract that half: kv[d][e] += sum_t K[d][t]V[e][t],
//        ksum[d] += sum_t K[d][t]; atomicAdd into global (pre-zeroed).
// 1D grid 1024, XCD swizzle: each XCD owns 16 m-panels x all 8 n.
// (MT=2 variant REGRESSED: persistent ckv/cks across GEMM spilled -> +53MB
//  scratch writes, 94->133us. Do not re-attempt without register budget.)
// ---------------------------------------------------------------------------
__global__ __launch_bounds__(256, 2) void kvfuse_kernel(
    const u16* __restrict__ A, const u16* __restrict__ Wk,
    const u16* __restrict__ Wv, const float* __restrict__ bk,
    const float* __restrict__ bv, float* __restrict__ kv,
    float* __restrict__ ksum)
{
    __shared__ __align__(16) char smem[49152];
    u16* As  = (u16*)smem;              // [128][64] staging
    u16* WKs = (u16*)(smem + 16384);
    u16* WVs = (u16*)(smem + 32768);

    const int tid  = threadIdx.x;
    const int w    = tid >> 6;
    const int lane = tid & 63;
    const int wm = w >> 1, wn = w & 1;
    const int quad = lane >> 4, l16 = lane & 15;

    // XCD swizzle: bid%8 ~ XCD; XCD k -> m-panels [k*16,(k+1)*16), all n
    const int bid = blockIdx.x;
    const int sw  = (bid & 7) * 128 + (bid >> 3);
    const int n0  = (sw & 7) * 128;      // head-pair channel base
    const int m0  = (sw >> 3) * 128;     // b*T row base

    const int srow = lane >> 3;
    const int scol = ((lane & 7) ^ srow) * 8;

    f32x4 ak[4][4], av[4][4];
    #pragma unroll
    for (int i = 0; i < 4; ++i)
        #pragma unroll
        for (int j = 0; j < 4; ++j) { ak[i][j] = (f32x4)0.0f; av[i][j] = (f32x4)0.0f; }

    for (int k0 = 0; k0 < CC; k0 += 64) {
        __syncthreads();
        #pragma unroll
        for (int s = 0; s < 4; ++s) {
            gl_lds16(A  + (size_t)(m0 + 32 * w + 8 * s + srow) * CC + k0 + scol,
                     &As [(32 * w + 8 * s) * 64]);
            gl_lds16(Wk + (size_t)(n0 + 32 * w + 8 * s + srow) * CC + k0 + scol,
                     &WKs[(32 * w + 8 * s) * 64]);
            gl_lds16(Wv + (size_t)(n0 + 32 * w + 8 * s + srow) * CC + k0 + scol,
                     &WVs[(32 * w + 8 * s) * 64]);
        }
        __syncthreads();

        #pragma unroll
        for (int sub = 0; sub < 2; ++sub) {
            const int pg = (((sub << 2) | quad) ^ (l16 & 7)) * 8;
            bf16x8 af[4], bk4[4], bv4[4];
            #pragma unroll
            for (int i = 0; i < 4; ++i) {
                af[i]  = *reinterpret_cast<const bf16x8*>(&As [(wm * 64 + i * 16 + l16) * 64 + pg]);
                bk4[i] = *reinterpret_cast<const bf16x8*>(&WKs[(wn * 64 + i * 16 + l16) * 64 + pg]);
                bv4[i] = *reinterpret_cast<const bf16x8*>(&WVs[(wn * 64 + i * 16 + l16) * 64 + pg]);
            }
            #pragma unroll
            for (int i = 0; i < 4; ++i)
                #pragma unroll
                for (int j = 0; j < 4; ++j) {
                    ak[i][j] = __builtin_amdgcn_mfma_f32_16x16x32_bf16(af[i], bk4[j], ak[i][j], 0, 0, 0);
                    av[i][j] = __builtin_amdgcn_mfma_f32_16x16x32_bf16(af[i], bv4[j], av[i][j], 0, 0, 0);
                }
        }
    }

    // ---- phases 2+3, two t-passes over [c:128][t:64] tiles (32 KB) ----
    u16* Kl = (u16*)smem;                  // [c:128][t:64] swizzled
    u16* Vl = (u16*)(smem + 16384);

    float bkk[4], bvv[4];
    #pragma unroll
    for (int j = 0; j < 4; ++j) {
        bkk[j] = bk[n0 + wn * 64 + j * 16 + l16];
        bvv[j] = bv[n0 + wn * 64 + j * 16 + l16];
    }

    const int hh    = w >> 1;              // head within pair (for contraction)
    const int dbase = (w & 1) * 32;        // this wave: d-tiles dbase, dbase+16
    const int b     = m0 >> 12;            // m0 / TT
    const int bh    = b * HH + (sw & 7) * 2 + hh;

    FragU ones;
    #pragma unroll
    for (int j = 0; j < 8; ++j) ones.u[j] = (l16 == 0) ? 0x3F80u : 0u;

    f32x4 ckv[2][4], cks[2];
    #pragma unroll
    for (int s = 0; s < 2; ++s) {
        cks[s] = (f32x4)0.0f;
        #pragma unroll
        for (int e4 = 0; e4 < 4; ++e4) ckv[s][e4] = (f32x4)0.0f;
    }

    #pragma unroll
    for (int h = 0; h < 2; ++h) {
        __syncthreads();                   // prior phase reads complete
        if (wm == h) {                     // waves owning this t-half write it
            #pragma unroll
            for (int i = 0; i < 4; ++i) {
                const int t6 = i * 16 + quad * 4;          // 0..60, 4-aligned
                #pragma unroll
                for (int j = 0; j < 4; ++j) {
                    const int c    = wn * 64 + j * 16 + l16;
                    const int toff = t6 ^ ((c & 7) * 8);   // stays in [0,64)
                    ushort4 oK, oV;
                    #pragma unroll
                    for (int r = 0; r < 4; ++r) {
                        float vK = ak[i][j][r] + bkk[j];
                        vK = (vK > 0.0f) ? (vK + 1.0f) : __expf(vK);
                        ((u16*)&oK)[r] = f2bf(vK);
                        ((u16*)&oV)[r] = f2bf(av[i][j][r] + bvv[j]);
                    }
                    *reinterpret_cast<ushort4*>(&Kl[c * 64 + toff]) = oK;
                    *reinterpret_cast<ushort4*>(&Vl[c * 64 + toff]) = oV;
                }
            }
        }
        __syncthreads();
        #pragma unroll
        for (int kt = 0; kt < 2; ++kt) {
            const int tg = kt * 32 + quad * 8;
            #pragma unroll
            for (int s = 0; s < 2; ++s) {
                const int ca = hh * 64 + dbase + s * 16 + l16;
                const bf16x8 af = *reinterpret_cast<const bf16x8*>(
                    &Kl[ca * 64 + (tg ^ ((ca & 7) * 8))]);
                #pragma unroll
                for (int e4 = 0; e4 < 4; ++e4) {
                    const int cb = hh * 64 + e4 * 16 + l16;
                    const bf16x8 bfv = *reinterpret_cast<const bf16x8*>(
                        &Vl[cb * 64 + (tg ^ ((cb & 7) * 8))]);
                    ckv[s][e4] = __builtin_amdgcn_mfma_f32_16x16x32_bf16(af, bfv, ckv[s][e4], 0, 0, 0);
                }
                cks[s] = __builtin_amdgcn_mfma_f32_16x16x32_bf16(af, ones.v, cks[s], 0, 0, 0);
            }
        }
    }

    float* kvb = kv + (size_t)bh * DD * DD;
    #pragma unroll
    for (int s = 0; s < 2; ++s)
        #pragma unroll
        for (int e4 = 0; e4 < 4; ++e4)
            #pragma unroll
            for (int r = 0; r < 4; ++r)
                atomicAdd(&kvb[(dbase + s * 16 + quad * 4 + r) * DD + e4 * 16 + l16],
                          ckv[s][e4][r]);
    if (l16 == 0) {
        #pragma unroll
        for (int s = 0; s < 2; ++s)
            #pragma unroll
            for (int r = 0; r < 4; ++r)
                atomicAdd(&ksum[bh * DD + dbase + s * 16 + quad * 4 + r], cks[s][r]);
    }
}

// ---------------------------------------------------------------------------
// qattn: Q-GEMM (N=1024) with attn fused in the epilogue (unchanged):
//   Q tile (bias+elu+1) -> swizzled LDS Qt[t:128][c:128]
//   then per wave (head hh=w>>1, t-half th=w&1): num = Q.kv, z = Q.ksum,
//   out = num/(z+1e-6) -> bf16 attn tile (kv/ksum from L2-hot global).
// 1D grid 1024 with XCD swizzle.
// ---------------------------------------------------------------------------
__global__ __launch_bounds__(256, 2) void qattn_kernel(
    const u16* __restrict__ A, const u16* __restrict__ Wq,
    const float* __restrict__ bq, const float* __restrict__ kv,
    const float* __restrict__ ksum, u16* __restrict__ attnO)
{
    __shared__ __align__(16) char smem[32768];
    u16* As = (u16*)smem;                  // [128][64]
    u16* Ws = (u16*)(smem + 16384);

    const int tid  = threadIdx.x;
    const int w    = tid >> 6;
    const int lane = tid & 63;
    const int wm = w >> 1, wn = w & 1;
    const int quad = lane >> 4, l16 = lane & 15;
    const int l7 = l16 & 7;

    const int bid = blockIdx.x;
    const int sw  = (bid & 7) * 128 + (bid >> 3);
    const int n0  = (sw & 7) * 128;
    const int m0  = (sw >> 3) * 128;

    const int srow = lane >> 3;
    const int scol = ((lane & 7) ^ srow) * 8;

    f32x4 acc[4][4];
    #pragma unroll
    for (int i = 0; i < 4; ++i)
        #pragma unroll
        for (int j = 0; j < 4; ++j) acc[i][j] = (f32x4)0.0f;

    for (int k0 = 0; k0 < CC; k0 += 64) {
        __syncthreads();
        #pragma unroll
        for (int s = 0; s < 4; ++s) {
            gl_lds16(A  + (size_t)(m0 + 32 * w + 8 * s + srow) * CC + k0 + scol,
                     &As[(32 * w + 8 * s) * 64]);
            gl_lds16(Wq + (size_t)(n0 + 32 * w + 8 * s + srow) * CC + k0 + scol,
                     &Ws[(32 * w + 8 * s) * 64]);
        }
        __syncthreads();

        #pragma unroll
        for (int sub = 0; sub < 2; ++sub) {
            const int pg = (((sub << 2) | quad) ^ l7) * 8;
            bf16x8 af[4], bfr[4];
            #pragma unroll
            for (int i = 0; i < 4; ++i) {
                af[i]  = *reinterpret_cast<const bf16x8*>(&As[(wm * 64 + i * 16 + l16) * 64 + pg]);
                bfr[i] = *reinterpret_cast<const bf16x8*>(&Ws[(wn * 64 + i * 16 + l16) * 64 + pg]);
            }
            #pragma unroll
            for (int i = 0; i < 4; ++i)
                #pragma unroll
                for (int j = 0; j < 4; ++j)
                    acc[i][j] = __builtin_amdgcn_mfma_f32_16x16x32_bf16(af[i], bfr[j], acc[i][j], 0, 0, 0);
        }
    }

    // ---- Q activation -> swizzled LDS tile ----
    __syncthreads();
    u16* Qt = (u16*)smem;                  // [t:128][c:128] swizzled
    float bqq[4];
    #pragma unroll
    for (int j = 0; j < 4; ++j) bqq[j] = bq[n0 + wn * 64 + j * 16 + l16];
    #pragma unroll
    for (int i = 0; i < 4; ++i) {
        #pragma unroll
        for (int j = 0; j < 4; ++j) {
            const int c = wn * 64 + j * 16 + l16;
            #pragma unroll
            for (int r = 0; r < 4; ++r) {
                const int t = wm * 64 + i * 16 + quad * 4 + r;
                float v = acc[i][j][r] + bqq[j];
                v = (v > 0.0f) ? (v + 1.0f) : __expf(v);
                Qt[t * 128 + (c ^ ((t & 7) * 8))] = f2bf(v);
            }
        }
    }
    __syncthreads();

    // ---- attn epilogue: wave -> head hh, t-half th ----
    const int hh = w >> 1, th = w & 1;
    const int b  = m0 >> 12;
    const int bh = b * HH + (sw & 7) * 2 + hh;
    const float* kvh = kv + (size_t)bh * DD * DD;

    FragU bf[4][2], zb[2];
    #pragma unroll
    for (int ck = 0; ck < 2; ++ck) {
        #pragma unroll
        for (int nt = 0; nt < 4; ++nt)
            #pragma unroll
            for (int j = 0; j < 8; ++j)
                bf[nt][ck].u[j] = f2bf(kvh[(ck * 32 + quad * 8 + j) * DD + nt * 16 + l16]);
        #pragma unroll
        for (int j = 0; j < 8; ++j)
            zb[ck].u[j] = (l16 == 0) ? f2bf(ksum[bh * DD + ck * 32 + quad * 8 + j]) : 0u;
    }

    f32x4 a2[4][4], za[4];
    #pragma unroll
    for (int i = 0; i < 4; ++i) {
        za[i] = (f32x4)0.0f;
        #pragma unroll
        for (int j = 0; j < 4; ++j) a2[i][j] = (f32x4)0.0f;
    }

    #pragma unroll
    for (int i = 0; i < 4; ++i) {
        const int trow = th * 64 + i * 16 + l16;
        #pragma unroll
        for (int ck = 0; ck < 2; ++ck) {
            const bf16x8 af = *reinterpret_cast<const bf16x8*>(
                &Qt[trow * 128 + (((hh * 8 + ck * 4 + quad) ^ l7) * 8)]);
            #pragma unroll
            for (int nt = 0; nt < 4; ++nt)
                a2[i][nt] = __builtin_amdgcn_mfma_f32_16x16x32_bf16(af, bf[nt][ck].v, a2[i][nt], 0, 0, 0);
            za[i] = __builtin_amdgcn_mfma_f32_16x16x32_bf16(af, zb[ck].v, za[i], 0, 0, 0);
        }
    }

    #pragma unroll
    for (int i = 0; i < 4; ++i) {
        float inv[4];
        #pragma unroll
        for (int r = 0; r < 4; ++r) {
            const float zv = __shfl(za[i][r], lane & 48);
            inv[r] = 1.0f / (zv + 1e-6f);
        }
        #pragma unroll
        for (int nt = 0; nt < 4; ++nt) {
            #pragma unroll
            for (int r = 0; r < 4; ++r) {
                const size_t row = (size_t)(m0 + th * 64 + i * 16 + quad * 4 + r);
                const int    col = n0 + hh * 64 + nt * 16 + l16;
                attnO[row * CC + col] = f2bf(a2[i][nt][r] * inv[r]);
            }
        }
    }
}

// ---------------------------------------------------------------------------
// Out-proj GEMM (MODE 2): 128x128 tile, +bias +fp32 residual, LDS-bounced
// fp32 stores along T.  1D grid 1024 with XCD swizzle. (unchanged)
// ---------------------------------------------------------------------------
template <int MODE>
__global__ __launch_bounds__(256, 2) void gemm_kernel(
    const u16* __restrict__ A, const u16* __restrict__ W,
    const float* __restrict__ b0, const float* __restrict__ b1,
    const float* __restrict__ b2, u16* __restrict__ Ybf,
    float* __restrict__ Yf, const float* __restrict__ xres,
    int M, int N, int K)
{
    __shared__ char smem[34048];           // As+Ws (32KB) / Cs (64*133*4)
    u16* As = (u16*)smem;                  // [128][64]
    u16* Ws = (u16*)(smem + 16384);        // [128][64]

    const int tid  = threadIdx.x;
    const int w    = tid >> 6;
    const int lane = tid & 63;
    const int wm = w >> 1, wn = w & 1;
    const int quad = lane >> 4, l16 = lane & 15;

    const int bid = blockIdx.x;
    const int sw  = (bid & 7) * 128 + (bid >> 3);
    const int n0  = (sw & 7) * 128;
    const int m0  = (sw >> 3) * 128;

    const int srow = lane >> 3;
    const int scol = ((lane & 7) ^ srow) * 8;

    f32x4 acc[4][4];
    #pragma unroll
    for (int i = 0; i < 4; ++i)
        #pragma unroll
        for (int j = 0; j < 4; ++j) acc[i][j] = (f32x4)0.0f;

    for (int k0 = 0; k0 < K; k0 += 64) {
        __syncthreads();
        #pragma unroll
        for (int s = 0; s < 4; ++s)
            gl_lds16(A + (size_t)(m0 + 32 * w + 8 * s + srow) * K + k0 + scol,
                     &As[(32 * w + 8 * s) * 64]);
        #pragma unroll
        for (int s = 0; s < 4; ++s)
            gl_lds16(W + (size_t)(n0 + 32 * w + 8 * s + srow) * K + k0 + scol,
                     &Ws[(32 * w + 8 * s) * 64]);
        __syncthreads();

        #pragma unroll
        for (int sub = 0; sub < 2; ++sub) {
            const int pg = (((sub << 2) | quad) ^ (l16 & 7)) * 8;
            bf16x8 af[4], bfr[4];
            #pragma unroll
            for (int i = 0; i < 4; ++i) {
                af[i]  = *reinterpret_cast<const bf16x8*>(&As[(wm * 64 + i * 16 + l16) * 64 + pg]);
                bfr[i] = *reinterpret_cast<const bf16x8*>(&Ws[(wn * 64 + i * 16 + l16) * 64 + pg]);
            }
            #pragma unroll
            for (int i = 0; i < 4; ++i)
                #pragma unroll
                for (int j = 0; j < 4; ++j)
                    acc[i][j] = __builtin_amdgcn_mfma_f32_16x16x32_bf16(af[i], bfr[j], acc[i][j], 0, 0, 0);
        }
    }

    if (MODE == 2) {
        float* Cs = (float*)smem;          // [64][133]
        const int b     = m0 / TT;
        const int tbase = m0 - b * TT;
        const int cl    = lane >> 4;
        #pragma unroll
        for (int hh = 0; hh < 2; ++hh) {
            __syncthreads();
            if (wm == hh) {
                #pragma unroll
                for (int i = 0; i < 4; ++i)
                    #pragma unroll
                    for (int j = 0; j < 4; ++j)
                        #pragma unroll
                        for (int r = 0; r < 4; ++r)
                            Cs[(i * 16 + quad * 4 + r) * 133 + wn * 64 + j * 16 + l16] = acc[i][j][r];
            }
            __syncthreads();
            #pragma unroll
            for (int p = 0; p < 8; ++p) {
                const int col = p * 16 + w * 4 + cl;
                const int tl  = l16 * 4;
                float4 v;
                v.x = Cs[(tl + 0) * 133 + col];
                v.y = Cs[(tl + 1) * 133 + col];
                v.z = Cs[(tl + 2) * 133 + col];
                v.w = Cs[(tl + 3) * 133 + col];
                const float bv = b0[n0 + col];
                const size_t base = ((size_t)b * CC + n0 + col) * TT + tbase + hh * 64 + tl;
                const float4 rx = *reinterpret_cast<const float4*>(&xres[base]);
                v.x += bv + rx.x; v.y += bv + rx.y;
                v.z += bv + rx.z; v.w += bv + rx.w;
                *reinterpret_cast<float4*>(&Yf[base]) = v;
            }
        }
    }
}

// ---------------------------------------------------------------------------
extern "C" void kernel_launch(void* const* d_in, const int* in_sizes, int n_in,
                              void* d_out, int out_size, void* d_ws, size_t ws_size,
                              hipStream_t stream)
{
    const float* x  = (const float*)d_in[0];
    const float* Wq = (const float*)d_in[1];
    const float* bq = (const float*)d_in[2];
    const float* Wk = (const float*)d_in[3];
    const float* bk = (const float*)d_in[4];
    const float* Wv = (const float*)d_in[5];
    const float* bv = (const float*)d_in[6];
    const float* Wo = (const float*)d_in[7];
    const float* bo = (const float*)d_in[8];
    float* out = (float*)d_out;

    const int M = BB * TT;                                   // 16384
    const size_t BUF  = (size_t)BB * TT * CC * sizeof(u16);  // 32 MiB
    const size_t WBUF = (size_t)CC * CC * sizeof(u16);       // 2 MiB

    char* ws = (char*)d_ws;
    u16* xt   = (u16*)(ws);                // xt bf16 [B*T][C]
    u16* Qb   = (u16*)(ws + BUF);          // attn output [B*T][C]
    u16* Wcat = (u16*)(ws + 4 * BUF);      // [3072][1024] bf16 (Q,K,V)
    u16* Wob  = (u16*)(ws + 4 * BUF + 3 * WBUF);
    float* kvbuf = (float*)(ws + 4 * BUF + 4 * WBUF);        // 1 MiB + 16 KiB (incl ksum)
    float* ksumb = kvbuf + (size_t)BB * HH * DD * DD;

    // prep: transpose (1024, float4-vectorized) + weight cvt (4096) + zero (260)
    prep_kernel<<<5380, 256, 0, stream>>>(x, Wq, Wk, Wv, Wo, xt, Wcat, Wob, kvbuf);

    // fused K/V GEMM + kv/ksum contraction (atomic accumulate), MT=1
    kvfuse_kernel<<<1024, 256, 0, stream>>>(
        xt, Wcat + (size_t)CC * CC, Wcat + 2 * (size_t)CC * CC, bk, bv, kvbuf, ksumb);

    // fused Q GEMM + attention epilogue -> attn tile in Qb
    qattn_kernel<<<1024, 256, 0, stream>>>(
        xt, Wcat, bq, kvbuf, ksumb, Qb);

    // out-proj + bias + residual -> fp32 [B][C][T]
    gemm_kernel<2><<<1024, 256, 0, stream>>>(
        Qb, Wob, bo, nullptr, nullptr, nullptr, out, x, M, CC, CC);
}